// Round 15
// baseline (636.730 us; speedup 1.0000x reference)
//
#include <hip/hip_runtime.h>
#include <stdint.h>

typedef int i32x4 __attribute__((ext_vector_type(4)));

#define D_DIM 4096   // K
#define O_DIM 4096   // N
#define M_DIM 16384  // M
#define THRESH 0.05f

// ---------- helpers ----------

__device__ __forceinline__ void gld16(const void* g, void* l) {
  __builtin_amdgcn_global_load_lds(
      (const __attribute__((address_space(1))) uint32_t*)(uintptr_t)g,
      (__attribute__((address_space(3))) uint32_t*)(uint32_t)(uintptr_t)l,
      16, 0, 0);
}

__device__ __forceinline__ int tern_i8(float v) {  // {-1,0,+1} as signed byte
  return (__builtin_fabsf(v) < THRESH) ? 0 : (v > 0.f ? 1 : -1);
}

// ---------- pre-pass kernels (r9 set: fastest measured) ----------

__global__ void k_scale_part(const float* __restrict__ w, float* __restrict__ part) {
  const int cg = blockIdx.x & 63;
  const int dz = blockIdx.x >> 6;
  const int tx = threadIdx.x & 63;
  const int ty = threadIdx.x >> 6;
  const int o = cg * 64 + tx;
  float s = 0.f;
  const float* p = w + (size_t)(dz * 512 + ty) * O_DIM + o;
  for (int i = 0; i < 128; ++i) {
    s += __builtin_fabsf(*p);
    p += 4 * O_DIM;
  }
  __shared__ float red[4][64];
  red[ty][tx] = s;
  __syncthreads();
  if (ty == 0) part[dz * O_DIM + o] = (red[0][tx] + red[1][tx]) + (red[2][tx] + red[3][tx]);
}

__global__ void k_scale_fin(const float* __restrict__ part, float* __restrict__ scale) {
  const int o = blockIdx.x * 256 + threadIdx.x;
  float s = 0.f;
#pragma unroll
  for (int z = 0; z < 8; ++z) s += part[z * O_DIM + o];
  scale[o] = s * (1.0f / 4096.0f);
}

// ternarize + transpose: w[d][o] f32 -> btq[o][d] i8 in {-1,0,1}; 64x64 tiles
__global__ void k_tern_q(const float* __restrict__ w, char* __restrict__ btq) {
  __shared__ char tile[64][68];
  const int ot = blockIdx.x & 63;
  const int dt = blockIdx.x >> 6;
  const int o0 = ot * 64, d0 = dt * 64;
  const int tx = threadIdx.x & 15, ty = threadIdx.x >> 4;
#pragma unroll
  for (int j = 0; j < 4; ++j) {
    const int r = ty + 16 * j;  // d_local
    const float4 v = *(const float4*)&w[(size_t)(d0 + r) * O_DIM + o0 + tx * 4];
    uint32_t u = (uint32_t)(tern_i8(v.x) & 0xFF) |
                 ((uint32_t)(tern_i8(v.y) & 0xFF) << 8) |
                 ((uint32_t)(tern_i8(v.z) & 0xFF) << 16) |
                 ((uint32_t)(tern_i8(v.w) & 0xFF) << 24);
    *(uint32_t*)&tile[r][tx * 4] = u;
  }
  __syncthreads();
#pragma unroll
  for (int j = 0; j < 4; ++j) {
    const int orow = ty + 16 * j;  // o_local
    uint32_t u = (uint32_t)((uint8_t)tile[tx * 4 + 0][orow]) |
                 ((uint32_t)((uint8_t)tile[tx * 4 + 1][orow]) << 8) |
                 ((uint32_t)((uint8_t)tile[tx * 4 + 2][orow]) << 16) |
                 ((uint32_t)((uint8_t)tile[tx * 4 + 3][orow]) << 24);
    *(uint32_t*)&btq[(size_t)(o0 + orow) * D_DIM + d0 + tx * 4] = u;
  }
}

// x f32 -> i8 with per-row symmetric scale (rowmax/127); one block per row
__global__ void k_quant(const float* __restrict__ x, char* __restrict__ xq,
                        float* __restrict__ sx) {
  const int row = blockIdx.x;
  const int t = threadIdx.x;  // 256
  const float* xr = x + (size_t)row * D_DIM + t * 16;
  float4 v[4];
#pragma unroll
  for (int i = 0; i < 4; ++i) v[i] = *(const float4*)(xr + i * 4);
  float m = 0.f;
#pragma unroll
  for (int i = 0; i < 4; ++i) {
    m = fmaxf(m, fmaxf(fmaxf(__builtin_fabsf(v[i].x), __builtin_fabsf(v[i].y)),
                       fmaxf(__builtin_fabsf(v[i].z), __builtin_fabsf(v[i].w))));
  }
#pragma unroll
  for (int off = 32; off >= 1; off >>= 1) m = fmaxf(m, __shfl_xor(m, off, 64));
  __shared__ float wm[4];
  if ((t & 63) == 0) wm[t >> 6] = m;
  __syncthreads();
  const float rm = fmaxf(fmaxf(wm[0], wm[1]), fmaxf(wm[2], wm[3]));
  const float inv = (rm > 0.f) ? 127.0f / rm : 0.0f;
  int4 o;
  int* op = (int*)&o;
#pragma unroll
  for (int i = 0; i < 4; ++i) {
    const float* f = (const float*)&v[i];
    uint32_t u = 0;
#pragma unroll
    for (int j = 0; j < 4; ++j) {
      float q = __builtin_rintf(f[j] * inv);
      q = fmaxf(-127.f, fminf(127.f, q));
      u |= ((uint32_t)((int)q & 0xFF)) << (8 * j);
    }
    op[i] = (int)u;
  }
  *(int4*)(xq + (size_t)row * D_DIM + t * 16) = o;
  if (t == 0) sx[row] = (rm > 0.f) ? rm * (1.0f / 127.0f) : 0.0f;
}

// ---------- 128x128 i8 GEMM, BK=128: B via LDS (32KB), A direct global->VGPR ----------
// acc_i32[m][n] = sum_k xq[m][k]*btq[n][k];  C = float(acc)*(sx[m]*scale[n]) + bias[n]
// 256 thr = 4 waves (2Mx2N), per-wave C = 64x64 (4x4 of 16x16), mfma_i32_16x16x64_i8.
// r14 is LDS-BW-bound (96KB traffic/block-tile ~ wall). This round halves LDS
// traffic: A fragments load directly global->VGPR (A panel 16KB, L2-resident via
// nb-fast swizzle; prefetched ONE FULL TILE ahead ~1200cyc - unlike r8's ~10-inst
// cover). LDS holds only B: 2buf x 16KB; traffic 48KB/block-tile -> MFMA-bound.
// A frag (m4,kk): lane l reads row = mBase+wr*64+m4*16+(l&15),
//                 bytes k = T*128 + kk*64 + (l>>4)*16  (16B) - exact i8 layout.
// B LDS image (r2..r14 measured-zero-conflict): granule (row,g) at byte
// row*128 + ((g^(row&7))<<4), staged via pre-swizzled GLOBAL src (dest linear).
// Calendar per tile T (buf d = T&1; aqC = parity T, aqN = parity T+1):
//   RB0+RB1 (8 dsr, B tile T)                 [reads buf d]
//   BAR1                                      [all waves issued buf-d reads]
//   STAGE_B(d, T+2)  (4 gld16)                [>=1 barrier after reads - r14 window]
//   LOADA(T+1 -> aqN) (8 plain loads)
//   VMW(12)  [newest 12 = own 4 stage + 8 loadA -> forces stage(T+1) + loadA(T)]
//   LGKM(4) -> MQ(0, aqC); LGKM(0) -> MQ(1, aqC)
//   BAR2                                      [publish]

#define BAR() __builtin_amdgcn_s_barrier()
#define SB0() __builtin_amdgcn_sched_barrier(0)
#define LGKM(n) asm volatile("s_waitcnt lgkmcnt(" #n ")" ::: "memory")
#define VMW(n) asm volatile("s_waitcnt vmcnt(" #n ")" ::: "memory")

#define STAGE_B(d, kv)                                                  \
  do {                                                                  \
    gld16(pB0 + (size_t)(kv) * 128, smem + (d)*16384 + t * 16);         \
    gld16(pB1 + (size_t)(kv) * 128, smem + (d)*16384 + 4096 + t * 16);  \
    gld16(pB2 + (size_t)(kv) * 128, smem + (d)*16384 + 8192 + t * 16);  \
    gld16(pB3 + (size_t)(kv) * 128, smem + (d)*16384 + 12288 + t * 16); \
  } while (0)

#define RB0(d)                                                           \
  do {                                                                   \
    const char* bb_ = smem + (d)*16384 + (wc * 64 + r16) * 128;          \
    _Pragma("unroll") for (int n4 = 0; n4 < 4; ++n4)                     \
        bq[0][n4] = *(const i32x4*)(bb_ + n4 * 2048 + slot0);            \
  } while (0)
#define RB1(d)                                                           \
  do {                                                                   \
    const char* bb_ = smem + (d)*16384 + (wc * 64 + r16) * 128;          \
    _Pragma("unroll") for (int n4 = 0; n4 < 4; ++n4)                     \
        bq[1][n4] = *(const i32x4*)(bb_ + n4 * 2048 + (slot0 ^ 64));     \
  } while (0)

#define LOADA(AQ, kv)                                                    \
  do {                                                                   \
    const size_t ko_ = (size_t)(kv) * 128;                               \
    AQ[0][0] = *(const i32x4*)(pAg0 + ko_);                              \
    AQ[1][0] = *(const i32x4*)(pAg0 + ko_ + 64);                         \
    AQ[0][1] = *(const i32x4*)(pAg1 + ko_);                              \
    AQ[1][1] = *(const i32x4*)(pAg1 + ko_ + 64);                         \
    AQ[0][2] = *(const i32x4*)(pAg2 + ko_);                              \
    AQ[1][2] = *(const i32x4*)(pAg2 + ko_ + 64);                         \
    AQ[0][3] = *(const i32x4*)(pAg3 + ko_);                              \
    AQ[1][3] = *(const i32x4*)(pAg3 + ko_ + 64);                         \
  } while (0)

#define MQ(kk, AC)                                                            \
  do {                                                                        \
    __builtin_amdgcn_s_setprio(1);                                            \
    _Pragma("unroll") for (int m4 = 0; m4 < 4; ++m4)                          \
    _Pragma("unroll") for (int n4 = 0; n4 < 4; ++n4)                          \
        acc[m4][n4] = __builtin_amdgcn_mfma_i32_16x16x64_i8(                  \
            AC[kk][m4], bq[kk][n4], acc[m4][n4], 0, 0, 0);                    \
    __builtin_amdgcn_s_setprio(0);                                            \
  } while (0)

#define TILE(d, AC, AN, Tv)                                              \
  do {                                                                   \
    RB0(d); RB1(d);                                                      \
    BAR();                                                               \
    STAGE_B(d, ((Tv) + 2) & 31);                                         \
    LOADA(AN, ((Tv) + 1) & 31);                                          \
    VMW(12); LGKM(4); SB0();                                             \
    MQ(0, AC);                                                           \
    LGKM(0); SB0();                                                      \
    MQ(1, AC);                                                           \
    BAR();                                                               \
  } while (0)

__global__ __launch_bounds__(256, 2) void k_gemm8(
    const char* __restrict__ A,   // xq [M][K] i8
    const char* __restrict__ B,   // btq [N][K] i8 (ternary)
    const float* __restrict__ sx, const float* __restrict__ scale,
    const float* __restrict__ bias, float* __restrict__ C) {
  __shared__ __align__(16) char smem[32768];

  // nb-FAST XCD swizzle (r13/r14): xcd owns nb in [xcd*4, xcd*4+4); A panel's 4
  // readers per XCD are time-adjacent (L2-resident A), B slice 2MB L2-resident.
  const int bid = blockIdx.x;
  const int xcd = bid & 7, s = bid >> 3;       // s in [0,512)
  const int nb = xcd * 4 + (s & 3);            // 32 nb, fast
  const int mb = s >> 2;                       // 128 mb, slow
  const int mBase = mb * 128, nBase = nb * 128;

  const int t = threadIdx.x;
  const int lane = t & 63, wid = t >> 6;
  const int wr = wid >> 1, wc = wid & 1;  // 2 x 2 waves
  const int r16 = lane & 15, kq = lane >> 4;
  const int slot0 = (kq ^ (r16 & 7)) << 4;

  // B staging: thread t stages granules t, t+256, t+512, t+768 of each 16KB tile
  const int sr0 = t >> 3, sg0 = (t & 7) ^ (sr0 & 7);
  const int q1 = 256 + t, q2 = 512 + t, q3 = 768 + t;
  const int sr1 = q1 >> 3, sg1 = (q1 & 7) ^ (sr1 & 7);
  const int sr2 = q2 >> 3, sg2 = (q2 & 7) ^ (sr2 & 7);
  const int sr3 = q3 >> 3, sg3 = (q3 & 7) ^ (sr3 & 7);

  const char* pB0 = B + (size_t)(nBase + sr0) * D_DIM + sg0 * 16;
  const char* pB1 = B + (size_t)(nBase + sr1) * D_DIM + sg1 * 16;
  const char* pB2 = B + (size_t)(nBase + sr2) * D_DIM + sg2 * 16;
  const char* pB3 = B + (size_t)(nBase + sr3) * D_DIM + sg3 * 16;

  // A direct-load per-lane bases (one per m4): row = mBase + wr*64 + m4*16 + r16
  const char* pAg0 = A + (size_t)(mBase + wr * 64 + 0 * 16 + r16) * D_DIM + kq * 16;
  const char* pAg1 = A + (size_t)(mBase + wr * 64 + 1 * 16 + r16) * D_DIM + kq * 16;
  const char* pAg2 = A + (size_t)(mBase + wr * 64 + 2 * 16 + r16) * D_DIM + kq * 16;
  const char* pAg3 = A + (size_t)(mBase + wr * 64 + 3 * 16 + r16) * D_DIM + kq * 16;

  i32x4 acc[4][4] = {};
  i32x4 aqA[2][4], aqB[2][4];  // [kk][m4], tile-parity double buffer
  i32x4 bq[2][4];              // [kk][n4]

  // prologue: B tile0 -> buf0, B tile1 -> buf1 (8 gld16); A tile0 -> aqA
  STAGE_B(0, 0);
  STAGE_B(1, 1);
  LOADA(aqA, 0);
  VMW(8);  // newest 8 = A loads -> forces both B stages; aqA forced at tile0's VMW(12)
  BAR();

  for (int T = 0; T < 32; T += 2) {
    TILE(0, aqA, aqB, T);      // computes tile T,   loads A(T+1), stages B(T+2)
    TILE(1, aqB, aqA, T + 1);  // computes tile T+1, loads A(T+2), stages B(T+3)
  }
  VMW(0);  // drain dummy wrap ops

  // epilogue: C/D mapping col=lane&15, row=4*(lane>>4)+r (verified r9-r14);
  // NON-TEMPORAL stores keep the 256MB C stream from evicting A/B panels (r12).
  float sxr[4][4];
#pragma unroll
  for (int mi = 0; mi < 4; ++mi) {
    const int gr0 = mBase + wr * 64 + mi * 16 + kq * 4;
#pragma unroll
    for (int r = 0; r < 4; ++r) sxr[mi][r] = sx[gr0 + r];
  }
#pragma unroll
  for (int ni = 0; ni < 4; ++ni) {
    const int gc = nBase + wc * 64 + ni * 16 + r16;
    const float sw = scale[gc];
    const float bb = bias[gc];
#pragma unroll
    for (int mi = 0; mi < 4; ++mi) {
      const int gr0 = mBase + wr * 64 + mi * 16 + kq * 4;
#pragma unroll
      for (int r = 0; r < 4; ++r) {
        __builtin_nontemporal_store(
            (float)acc[mi][ni][r] * (sxr[mi][r] * sw) + bb,
            &C[(size_t)(gr0 + r) * O_DIM + gc]);
      }
    }
  }
}

// ---------- launch ----------

extern "C" void kernel_launch(void* const* d_in, const int* in_sizes, int n_in,
                              void* d_out, int out_size, void* d_ws, size_t ws_size,
                              hipStream_t stream) {
  const float* x = (const float*)d_in[0];
  const float* w = (const float*)d_in[1];
  const float* bias = (const float*)d_in[2];
  float* out = (float*)d_out;

  const size_t XQ_OFF = 0;                                    // 64MB
  const size_t BT_OFF = (size_t)M_DIM * D_DIM;                // +16MB
  const size_t SX_OFF = BT_OFF + (size_t)O_DIM * D_DIM;       // +64KB
  const size_t PART_OFF = SX_OFF + (size_t)M_DIM * 4;
  const size_t SCALE_OFF = PART_OFF + 8 * O_DIM * 4;
  const size_t NEED = SCALE_OFF + O_DIM * 4;
  if (ws_size < NEED) return;

  char* ws = (char*)d_ws;
  char* xq = ws + XQ_OFF;
  char* btq = ws + BT_OFF;
  float* sx = (float*)(ws + SX_OFF);
  float* part = (float*)(ws + PART_OFF);
  float* scale = (float*)(ws + SCALE_OFF);

  k_scale_part<<<512, 256, 0, stream>>>(w, part);
  k_scale_fin<<<16, 256, 0, stream>>>(part, scale);
  k_tern_q<<<64 * 64, 256, 0, stream>>>(w, btq);
  k_quant<<<M_DIM, 256, 0, stream>>>(x, xq, sx);
  k_gemm8<<<4096, 256, 0, stream>>>(xq, btq, sx, scale, bias, out);
}

// Round 16
// 318.011 us; speedup vs baseline: 2.0022x; 2.0022x over previous
//
#include <hip/hip_runtime.h>
#include <stdint.h>

typedef int i32x4 __attribute__((ext_vector_type(4)));

#define D_DIM 4096   // K
#define O_DIM 4096   // N
#define M_DIM 16384  // M
#define THRESH 0.05f

// ---------- helpers ----------

__device__ __forceinline__ void gld16(const void* g, void* l) {
  __builtin_amdgcn_global_load_lds(
      (const __attribute__((address_space(1))) uint32_t*)(uintptr_t)g,
      (__attribute__((address_space(3))) uint32_t*)(uint32_t)(uintptr_t)l,
      16, 0, 0);
}

__device__ __forceinline__ int tern_i8(float v) {  // {-1,0,+1} as signed byte
  return (__builtin_fabsf(v) < THRESH) ? 0 : (v > 0.f ? 1 : -1);
}

// ---------- pre-pass kernels (r9 set: fastest measured) ----------

__global__ void k_scale_part(const float* __restrict__ w, float* __restrict__ part) {
  const int cg = blockIdx.x & 63;
  const int dz = blockIdx.x >> 6;
  const int tx = threadIdx.x & 63;
  const int ty = threadIdx.x >> 6;
  const int o = cg * 64 + tx;
  float s = 0.f;
  const float* p = w + (size_t)(dz * 512 + ty) * O_DIM + o;
  for (int i = 0; i < 128; ++i) {
    s += __builtin_fabsf(*p);
    p += 4 * O_DIM;
  }
  __shared__ float red[4][64];
  red[ty][tx] = s;
  __syncthreads();
  if (ty == 0) part[dz * O_DIM + o] = (red[0][tx] + red[1][tx]) + (red[2][tx] + red[3][tx]);
}

__global__ void k_scale_fin(const float* __restrict__ part, float* __restrict__ scale) {
  const int o = blockIdx.x * 256 + threadIdx.x;
  float s = 0.f;
#pragma unroll
  for (int z = 0; z < 8; ++z) s += part[z * O_DIM + o];
  scale[o] = s * (1.0f / 4096.0f);
}

// ternarize + transpose: w[d][o] f32 -> btq[o][d] i8 in {-1,0,1}; 64x64 tiles
__global__ void k_tern_q(const float* __restrict__ w, char* __restrict__ btq) {
  __shared__ char tile[64][68];
  const int ot = blockIdx.x & 63;
  const int dt = blockIdx.x >> 6;
  const int o0 = ot * 64, d0 = dt * 64;
  const int tx = threadIdx.x & 15, ty = threadIdx.x >> 4;
#pragma unroll
  for (int j = 0; j < 4; ++j) {
    const int r = ty + 16 * j;  // d_local
    const float4 v = *(const float4*)&w[(size_t)(d0 + r) * O_DIM + o0 + tx * 4];
    uint32_t u = (uint32_t)(tern_i8(v.x) & 0xFF) |
                 ((uint32_t)(tern_i8(v.y) & 0xFF) << 8) |
                 ((uint32_t)(tern_i8(v.z) & 0xFF) << 16) |
                 ((uint32_t)(tern_i8(v.w) & 0xFF) << 24);
    *(uint32_t*)&tile[r][tx * 4] = u;
  }
  __syncthreads();
#pragma unroll
  for (int j = 0; j < 4; ++j) {
    const int orow = ty + 16 * j;  // o_local
    uint32_t u = (uint32_t)((uint8_t)tile[tx * 4 + 0][orow]) |
                 ((uint32_t)((uint8_t)tile[tx * 4 + 1][orow]) << 8) |
                 ((uint32_t)((uint8_t)tile[tx * 4 + 2][orow]) << 16) |
                 ((uint32_t)((uint8_t)tile[tx * 4 + 3][orow]) << 24);
    *(uint32_t*)&btq[(size_t)(o0 + orow) * D_DIM + d0 + tx * 4] = u;
  }
}

// x f32 -> i8 with per-row symmetric scale (rowmax/127); one block per row
__global__ void k_quant(const float* __restrict__ x, char* __restrict__ xq,
                        float* __restrict__ sx) {
  const int row = blockIdx.x;
  const int t = threadIdx.x;  // 256
  const float* xr = x + (size_t)row * D_DIM + t * 16;
  float4 v[4];
#pragma unroll
  for (int i = 0; i < 4; ++i) v[i] = *(const float4*)(xr + i * 4);
  float m = 0.f;
#pragma unroll
  for (int i = 0; i < 4; ++i) {
    m = fmaxf(m, fmaxf(fmaxf(__builtin_fabsf(v[i].x), __builtin_fabsf(v[i].y)),
                       fmaxf(__builtin_fabsf(v[i].z), __builtin_fabsf(v[i].w))));
  }
#pragma unroll
  for (int off = 32; off >= 1; off >>= 1) m = fmaxf(m, __shfl_xor(m, off, 64));
  __shared__ float wm[4];
  if ((t & 63) == 0) wm[t >> 6] = m;
  __syncthreads();
  const float rm = fmaxf(fmaxf(wm[0], wm[1]), fmaxf(wm[2], wm[3]));
  const float inv = (rm > 0.f) ? 127.0f / rm : 0.0f;
  int4 o;
  int* op = (int*)&o;
#pragma unroll
  for (int i = 0; i < 4; ++i) {
    const float* f = (const float*)&v[i];
    uint32_t u = 0;
#pragma unroll
    for (int j = 0; j < 4; ++j) {
      float q = __builtin_rintf(f[j] * inv);
      q = fmaxf(-127.f, fminf(127.f, q));
      u |= ((uint32_t)((int)q & 0xFF)) << (8 * j);
    }
    op[i] = (int)u;
  }
  *(int4*)(xq + (size_t)row * D_DIM + t * 16) = o;
  if (t == 0) sx[row] = (rm > 0.f) ? rm * (1.0f / 127.0f) : 0.0f;
}

// ---------- 128x128 i8 GEMM, BK=128, 2 independent blocks/CU, 2-barrier tile ----------
// (r14 verbatim — best measured: GEMM ~256us, ~2150 TOPS, 55% of i8 ceiling)
// acc_i32[m][n] = sum_k xq[m][k]*btq[n][k];  C = float(acc)*(sx[m]*scale[n]) + bias[n]
// 256 thr = 4 waves (2Mx2N), per-wave C = 64x64 (4x4 of 16x16), mfma_i32_16x16x64_i8.
// LDS 64KB -> 2 blocks/CU, UNSYNCHRONIZED anti-phase overlap.
// LDS image (r2..r14 measured-zero-conflict): granule (row,g) at byte
// row*128 + ((g^(row&7))<<4), staged via pre-swizzled GLOBAL src (dest linear).
// Calendar per tile T (buf d = T&1), stages target T+2 -> buf d:
//   RA0+RB0 (kk0, 8 dsr); RA1+RB1 (kk1, 8 dsr);
//   BAR1; STAGE_A+STAGE_B(d, T+2); LGKM(8)->MQ(0); LGKM(0)->MQ(1);
//   VMW(8) [newest 8 = own stages -> T+1 resident]; BAR2.

#define BAR() __builtin_amdgcn_s_barrier()
#define SB0() __builtin_amdgcn_sched_barrier(0)
#define LGKM(n) asm volatile("s_waitcnt lgkmcnt(" #n ")" ::: "memory")
#define VMW(n) asm volatile("s_waitcnt vmcnt(" #n ")" ::: "memory")

#define STAGE_A(d, kv)                                              \
  do {                                                              \
    gld16(pA0 + (size_t)(kv) * 128, smem + (d)*16384 + t * 16);     \
    gld16(pA1 + (size_t)(kv) * 128, smem + (d)*16384 + 4096 + t * 16); \
    gld16(pA2 + (size_t)(kv) * 128, smem + (d)*16384 + 8192 + t * 16); \
    gld16(pA3 + (size_t)(kv) * 128, smem + (d)*16384 + 12288 + t * 16); \
  } while (0)
#define STAGE_B(d, kv)                                              \
  do {                                                              \
    gld16(pB0 + (size_t)(kv) * 128, smem + 32768 + (d)*16384 + t * 16); \
    gld16(pB1 + (size_t)(kv) * 128, smem + 32768 + (d)*16384 + 4096 + t * 16); \
    gld16(pB2 + (size_t)(kv) * 128, smem + 32768 + (d)*16384 + 8192 + t * 16); \
    gld16(pB3 + (size_t)(kv) * 128, smem + 32768 + (d)*16384 + 12288 + t * 16); \
  } while (0)

#define RA0(d)                                                         \
  do {                                                                 \
    const char* ab_ = smem + (d)*16384 + (wr * 64 + r16) * 128;        \
    _Pragma("unroll") for (int m4 = 0; m4 < 4; ++m4)                   \
        aq[0][m4] = *(const i32x4*)(ab_ + m4 * 2048 + slot0);          \
  } while (0)
#define RA1(d)                                                         \
  do {                                                                 \
    const char* ab_ = smem + (d)*16384 + (wr * 64 + r16) * 128;        \
    _Pragma("unroll") for (int m4 = 0; m4 < 4; ++m4)                   \
        aq[1][m4] = *(const i32x4*)(ab_ + m4 * 2048 + (slot0 ^ 64));   \
  } while (0)
#define RB0(d)                                                         \
  do {                                                                 \
    const char* bb_ = smem + 32768 + (d)*16384 + (wc * 64 + r16) * 128; \
    _Pragma("unroll") for (int n4 = 0; n4 < 4; ++n4)                   \
        bq[0][n4] = *(const i32x4*)(bb_ + n4 * 2048 + slot0);          \
  } while (0)
#define RB1(d)                                                         \
  do {                                                                 \
    const char* bb_ = smem + 32768 + (d)*16384 + (wc * 64 + r16) * 128; \
    _Pragma("unroll") for (int n4 = 0; n4 < 4; ++n4)                   \
        bq[1][n4] = *(const i32x4*)(bb_ + n4 * 2048 + (slot0 ^ 64));   \
  } while (0)

#define MQ(kk)                                                                \
  do {                                                                        \
    __builtin_amdgcn_s_setprio(1);                                            \
    _Pragma("unroll") for (int m4 = 0; m4 < 4; ++m4)                          \
    _Pragma("unroll") for (int n4 = 0; n4 < 4; ++n4)                          \
        acc[m4][n4] = __builtin_amdgcn_mfma_i32_16x16x64_i8(                  \
            aq[kk][m4], bq[kk][n4], acc[m4][n4], 0, 0, 0);                    \
    __builtin_amdgcn_s_setprio(0);                                            \
  } while (0)

#define TILE(d, kv)                                                      \
  do {                                                                   \
    RA0(d); RB0(d);                                                      \
    RA1(d); RB1(d);                                                      \
    BAR();                                                               \
    STAGE_A(d, kv); STAGE_B(d, kv);                                      \
    LGKM(8); SB0();                                                      \
    MQ(0);                                                               \
    LGKM(0); SB0();                                                      \
    MQ(1);                                                               \
    VMW(8); BAR();                                                       \
  } while (0)

__global__ __launch_bounds__(256, 2) void k_gemm8(
    const char* __restrict__ A,   // xq [M][K] i8
    const char* __restrict__ B,   // btq [N][K] i8 (ternary)
    const float* __restrict__ sx, const float* __restrict__ scale,
    const float* __restrict__ bias, float* __restrict__ C) {
  __shared__ __align__(16) char smem[65536];

  // nb-FAST XCD swizzle (r13): xcd owns nb in [xcd*4, xcd*4+4); A panel's 4
  // readers per XCD are time-adjacent; all XCDs sweep the same mb band together.
  const int bid = blockIdx.x;
  const int xcd = bid & 7, s = bid >> 3;       // s in [0,512)
  const int nb = xcd * 4 + (s & 3);            // 32 nb, fast
  const int mb = s >> 2;                       // 128 mb, slow
  const int mBase = mb * 128, nBase = nb * 128;

  const int t = threadIdx.x;
  const int lane = t & 63, wid = t >> 6;
  const int wr = wid >> 1, wc = wid & 1;  // 2 x 2 waves
  const int r16 = lane & 15, kq = lane >> 4;
  const int slot0 = (kq ^ (r16 & 7)) << 4;

  // staging: thread t stages granules t, t+256, t+512, t+768 of each 16KB tile
  const int sr0 = t >> 3, sg0 = (t & 7) ^ (sr0 & 7);        // q0 = t
  const int q1 = 256 + t, q2 = 512 + t, q3 = 768 + t;
  const int sr1 = q1 >> 3, sg1 = (q1 & 7) ^ (sr1 & 7);
  const int sr2 = q2 >> 3, sg2 = (q2 & 7) ^ (sr2 & 7);
  const int sr3 = q3 >> 3, sg3 = (q3 & 7) ^ (sr3 & 7);

  const char* pA0 = A + (size_t)(mBase + sr0) * D_DIM + sg0 * 16;
  const char* pA1 = A + (size_t)(mBase + sr1) * D_DIM + sg1 * 16;
  const char* pA2 = A + (size_t)(mBase + sr2) * D_DIM + sg2 * 16;
  const char* pA3 = A + (size_t)(mBase + sr3) * D_DIM + sg3 * 16;
  const char* pB0 = B + (size_t)(nBase + sr0) * D_DIM + sg0 * 16;
  const char* pB1 = B + (size_t)(nBase + sr1) * D_DIM + sg1 * 16;
  const char* pB2 = B + (size_t)(nBase + sr2) * D_DIM + sg2 * 16;
  const char* pB3 = B + (size_t)(nBase + sr3) * D_DIM + sg3 * 16;

  i32x4 acc[4][4] = {};
  i32x4 aq[2][4];  // [kk][m4]
  i32x4 bq[2][4];  // [kk][n4]

  // prologue: tile0 -> buf0, tile1 -> buf1; force tile0
  STAGE_A(0, 0); STAGE_B(0, 0);
  STAGE_A(1, 1); STAGE_B(1, 1);
  VMW(8);  // newest 8 = tile1's stages -> tile0 resident
  BAR();

  for (int T = 0; T < 32; T += 2) {
    TILE(0, (T + 2) & 31);  // tiles 30/31 stage dummy wrap (never read)
    TILE(1, (T + 3) & 31);
  }
  VMW(0);  // drain dummy stages

  // epilogue: C/D mapping col=lane&15, row=4*(lane>>4)+r (verified r9-r14);
  // NON-TEMPORAL stores keep the 256MB C stream from evicting A/B panels (r12).
  float sxr[4][4];
#pragma unroll
  for (int mi = 0; mi < 4; ++mi) {
    const int gr0 = mBase + wr * 64 + mi * 16 + kq * 4;
#pragma unroll
    for (int r = 0; r < 4; ++r) sxr[mi][r] = sx[gr0 + r];
  }
#pragma unroll
  for (int ni = 0; ni < 4; ++ni) {
    const int gc = nBase + wc * 64 + ni * 16 + r16;
    const float sw = scale[gc];
    const float bb = bias[gc];
#pragma unroll
    for (int mi = 0; mi < 4; ++mi) {
      const int gr0 = mBase + wr * 64 + mi * 16 + kq * 4;
#pragma unroll
      for (int r = 0; r < 4; ++r) {
        __builtin_nontemporal_store(
            (float)acc[mi][ni][r] * (sxr[mi][r] * sw) + bb,
            &C[(size_t)(gr0 + r) * O_DIM + gc]);
      }
    }
  }
}

// ---------- launch ----------

extern "C" void kernel_launch(void* const* d_in, const int* in_sizes, int n_in,
                              void* d_out, int out_size, void* d_ws, size_t ws_size,
                              hipStream_t stream) {
  const float* x = (const float*)d_in[0];
  const float* w = (const float*)d_in[1];
  const float* bias = (const float*)d_in[2];
  float* out = (float*)d_out;

  const size_t XQ_OFF = 0;                                    // 64MB
  const size_t BT_OFF = (size_t)M_DIM * D_DIM;                // +16MB
  const size_t SX_OFF = BT_OFF + (size_t)O_DIM * D_DIM;       // +64KB
  const size_t PART_OFF = SX_OFF + (size_t)M_DIM * 4;
  const size_t SCALE_OFF = PART_OFF + 8 * O_DIM * 4;
  const size_t NEED = SCALE_OFF + O_DIM * 4;
  if (ws_size < NEED) return;

  char* ws = (char*)d_ws;
  char* xq = ws + XQ_OFF;
  char* btq = ws + BT_OFF;
  float* sx = (float*)(ws + SX_OFF);
  float* part = (float*)(ws + PART_OFF);
  float* scale = (float*)(ws + SCALE_OFF);

  k_scale_part<<<512, 256, 0, stream>>>(w, part);
  k_scale_fin<<<16, 256, 0, stream>>>(part, scale);
  k_tern_q<<<64 * 64, 256, 0, stream>>>(w, btq);
  k_quant<<<M_DIM, 256, 0, stream>>>(x, xq, sx);
  k_gemm8<<<4096, 256, 0, stream>>>(xq, btq, sx, scale, bias, out);
}